// Round 3
// baseline (611.811 us; speedup 1.0000x reference)
//
#include <hip/hip_runtime.h>
#include <math.h>

#define NEGV -10000000.0f

constexpr int B_ = 8, T_ = 16;
constexpr int QALL = 256, QRES = 128, QARG = 192;
constexpr int STATE = 256, VOCAB = 10000;
constexpr int WT = 128;
constexpr int NWT = (VOCAB + WT - 1) / WT;   // 79
constexpr int AT = 32;                       // emit a-rows per block

// ---- workspace layout (units of 4 bytes) ----
constexpr size_t OFF_CHART = 0;                                    // chart[ell][s][b][a]
constexpr size_t CHART_SZ  = (size_t)T_ * T_ * B_ * QALL;          // 524288
constexpr size_t OFF_EGR   = OFF_CHART + CHART_SZ;                 // exp(G_rarg) [j][r]
constexpr size_t OFF_EGL   = OFF_EGR + (size_t)QARG * QRES;        // exp(G_larg) [j][r]
constexpr size_t OFF_LF    = OFF_EGL + (size_t)QARG * QRES;        // lfunc transposed [j][r] (int)
constexpr size_t OFF_RF    = OFF_LF + (size_t)QARG * QRES;         // rfunc transposed [j][r] (int)
constexpr size_t OFF_S0    = OFF_RF + (size_t)QARG * QRES;         // split_scores[:,0] per a (256)
constexpr size_t OFF_S1    = OFF_S0 + QALL;                        // split_scores[:,1] per a (256)
constexpr size_t OFF_PM    = OFF_S1 + QALL;                        // emit partial max [wt][a]
constexpr size_t OFF_PS    = OFF_PM + (size_t)NWT * QALL;          // emit partial sum [wt][a]
constexpr size_t OFF_LSE   = OFF_PS + (size_t)NWT * QALL;          // emit row lse (256)
// ~690k floats ~ 2.76 MB

__device__ __forceinline__ size_t chIdx(int ell, int s, int b) {
    return OFF_CHART + ((size_t)((ell * 16 + s) * 8 + b)) * 256;
}

__device__ __forceinline__ float waveMax(float v) {
    #pragma unroll
    for (int m = 32; m >= 1; m >>= 1) v = fmaxf(v, __shfl_xor(v, m, 64));
    return v;
}
__device__ __forceinline__ float waveSum(float v) {
    #pragma unroll
    for (int m = 32; m >= 1; m >>= 1) v += __shfl_xor(v, m, 64);
    return v;
}
// all-threads block reductions (uniform call). trailing sync protects scratch reuse.
__device__ __forceinline__ float blockMax(float v, float* scr, int nw) {
    int lane = threadIdx.x & 63, w = threadIdx.x >> 6;
    v = waveMax(v);
    if (lane == 0) scr[w] = v;
    __syncthreads();
    float r = scr[0];
    for (int i = 1; i < nw; i++) r = fmaxf(r, scr[i]);
    __syncthreads();
    return r;
}
__device__ __forceinline__ float blockSum(float v, float* scr, int nw) {
    int lane = threadIdx.x & 63, w = threadIdx.x >> 6;
    v = waveSum(v);
    if (lane == 0) scr[w] = v;
    __syncthreads();
    float r = 0.f;
    for (int i = 0; i < nw; i++) r += scr[i];
    __syncthreads();
    return r;
}

// ---------------- G tables: log_softmax(rule_W+rule_b) + assoc, exp'd + transposed ----------------
__global__ __launch_bounds__(192) void prep_g_kernel(
        const float* __restrict__ rule_W, const float* __restrict__ rule_b,
        const float* __restrict__ assoc,
        const float* __restrict__ larg_mask, const float* __restrict__ rarg_mask,
        const int* __restrict__ lfunc, const int* __restrict__ rfunc,
        float* __restrict__ ws) {
    __shared__ float scr[4];
    int r = blockIdx.x;      // 0..127
    int j = threadIdx.x;     // 0..191
    float v0 = rule_W[r * 2 * QARG + j] + rule_b[j];
    float v1 = rule_W[r * 2 * QARG + QARG + j] + rule_b[QARG + j];
    float m = blockMax(fmaxf(v0, v1), scr, 3);
    float s = blockSum(expf(v0 - m) + expf(v1 - m), scr, 3);
    float l = m + logf(s);
    float av = assoc[r * QARG + j];
    float gl = v0 - l + av + larg_mask[r * QARG + j];
    float gr = v1 - l + av + rarg_mask[r * QARG + j];
    ws[OFF_EGL + (size_t)j * QRES + r] = expf(gl);
    ws[OFF_EGR + (size_t)j * QRES + r] = expf(gr);
    ((int*)ws)[OFF_LF + (size_t)j * QRES + r] = lfunc[r * QARG + j];
    ((int*)ws)[OFF_RF + (size_t)j * QRES + r] = rfunc[r * QARG + j];
}

// ---------------- split-score MLP (1024 threads, split-K x4, latency-hiding structure) ----------------
#define MLP_MATVEC(INBUF, W, RES) do {                                          \
    float acc_ = 0.f;                                                           \
    _Pragma("unroll 16")                                                        \
    for (int s_ = 0; s_ < 64; s_++)                                             \
        acc_ += INBUF[s0 + s_] * W[(s0 + s_) * STATE + col];                    \
    part[t] = acc_;                                                             \
    __syncthreads();                                                            \
    RES = part[col] + part[STATE + col] + part[2 * STATE + col]                 \
        + part[3 * STATE + col];                                                \
} while (0)

__global__ __launch_bounds__(1024) void mlp_kernel(
        const float* __restrict__ nt_emb,
        const float* __restrict__ sw1, const float* __restrict__ sb1,
        const float* __restrict__ r1w1, const float* __restrict__ r1b1,
        const float* __restrict__ r1w2, const float* __restrict__ r1b2,
        const float* __restrict__ r2w1, const float* __restrict__ r2b1,
        const float* __restrict__ r2w2, const float* __restrict__ r2b2,
        const float* __restrict__ sw2, const float* __restrict__ sb2,
        float* __restrict__ ws) {
    __shared__ float xin[STATE], hbuf[STATE], tbuf[STATE];
    __shared__ float part[4 * STATE];
    __shared__ float scr[16];
    int a = blockIdx.x, t = threadIdx.x;
    int col = t & 255;
    int grp = t >> 8;        // 0..3
    int s0 = grp * 64;       // this group's K-range
    if (t < STATE) xin[t] = nt_emb[a * STATE + t];
    __syncthreads();
    float r;
    MLP_MATVEC(xin, sw1, r);
    if (grp == 0) hbuf[col] = r + sb1[col];
    __syncthreads();
    MLP_MATVEC(hbuf, r1w1, r);
    if (grp == 0) tbuf[col] = fmaxf(r + r1b1[col], 0.f);
    __syncthreads();
    MLP_MATVEC(tbuf, r1w2, r);
    if (grp == 0) hbuf[col] += fmaxf(r + r1b2[col], 0.f);
    __syncthreads();
    MLP_MATVEC(hbuf, r2w1, r);
    if (grp == 0) tbuf[col] = fmaxf(r + r2b1[col], 0.f);
    __syncthreads();
    MLP_MATVEC(tbuf, r2w2, r);
    if (grp == 0) hbuf[col] += fmaxf(r + r2b2[col], 0.f);
    __syncthreads();
    float hv = (t < STATE) ? hbuf[t] : 0.f;
    float v0 = (t < STATE) ? hv * sw2[t * 2 + 0] : 0.f;
    float v1 = (t < STATE) ? hv * sw2[t * 2 + 1] : 0.f;
    float u0 = blockSum(v0, scr, 16) + sb2[0];
    float u1 = blockSum(v1, scr, 16) + sb2[1];
    if (t == 0) {
        float mm = fmaxf(u0, u1);
        float l = mm + logf(expf(u0 - mm) + expf(u1 - mm));
        ws[OFF_S0 + a] = u0 - l;
        ws[OFF_S1 + a] = u1 - l;
    }
}

// ---------------- emit GEMM with fused partial row-logsumexp ----------------
// a-dim split into 8 tiles of 32 rows -> 632 blocks (was 316): grid-limited occupancy fix.
__global__ __launch_bounds__(256) void emit_kernel(
        const float* __restrict__ nt_emb, const float* __restrict__ W_emit,
        const float* __restrict__ b_emit, float* __restrict__ ws) {
    __shared__ float As[16][AT];        // [kk][aa]
    __shared__ float Bs[16][128];       // [kk][ww]
    __shared__ float redM[AT][16], redS[AT][16];
    int wt = blockIdx.x, at = blockIdx.y;
    int t = threadIdx.x;
    int tx = t & 15, ty = t >> 4;
    float acc[2][8];
    #pragma unroll
    for (int i = 0; i < 2; i++)
        #pragma unroll
        for (int j = 0; j < 8; j++) acc[i][j] = 0.f;
    int wbase = wt * WT, abase = at * AT;
    for (int k0 = 0; k0 < STATE; k0 += 16) {
        { // stage A: 512 floats / 256 threads = 2/thread (float2), transposed to [kk][aa]
            int idx = t * 2;
            int kk = idx & 15, aa = idx >> 4;
            float2 v = *(const float2*)&nt_emb[(abase + aa) * STATE + k0 + kk];
            As[kk + 0][aa] = v.x; As[kk + 1][aa] = v.y;
        }
        { // stage B: 8 floats/thread
            int idx = t * 8;
            int kk = idx >> 7, ww = idx & 127;
            int w = wbase + ww;
            const float* src = &W_emit[(k0 + kk) * VOCAB + w];
            float4 v0, v1;
            if (w + 7 < VOCAB) {
                v0 = *(const float4*)src;
                v1 = *(const float4*)(src + 4);
            } else {
                float tv[8];
                #pragma unroll
                for (int q = 0; q < 8; q++) tv[q] = (w + q < VOCAB) ? src[q] : 0.f;
                v0 = make_float4(tv[0], tv[1], tv[2], tv[3]);
                v1 = make_float4(tv[4], tv[5], tv[6], tv[7]);
            }
            float* dst = &Bs[kk][ww];
            ((float4*)dst)[0] = v0;
            ((float4*)dst)[1] = v1;
        }
        __syncthreads();
        #pragma unroll
        for (int kk = 0; kk < 16; kk++) {
            float a2[2], b8[8];
            #pragma unroll
            for (int i = 0; i < 2; i++) a2[i] = As[kk][ty * 2 + i];
            #pragma unroll
            for (int j = 0; j < 8; j++) b8[j] = Bs[kk][tx * 8 + j];
            #pragma unroll
            for (int i = 0; i < 2; i++)
                #pragma unroll
                for (int j = 0; j < 8; j++) acc[i][j] += a2[i] * b8[j];
        }
        __syncthreads();
    }
    // epilogue: + b_emit, per-row partial (max,sumexp) over the 128 w of this tile
    float be[8];
    #pragma unroll
    for (int j = 0; j < 8; j++) {
        int w = wbase + tx * 8 + j;
        be[j] = (w < VOCAB) ? b_emit[w] : 0.f;
    }
    #pragma unroll
    for (int i = 0; i < 2; i++) {
        float mloc = -3.0e38f;
        #pragma unroll
        for (int j = 0; j < 8; j++) {
            int w = wbase + tx * 8 + j;
            if (w < VOCAB) {
                float v = acc[i][j] + be[j];
                acc[i][j] = v;
                mloc = fmaxf(mloc, v);
            }
        }
        float sloc = 0.f;
        #pragma unroll
        for (int j = 0; j < 8; j++) {
            int w = wbase + tx * 8 + j;
            if (w < VOCAB) sloc += expf(acc[i][j] - mloc);
        }
        redM[ty * 2 + i][tx] = mloc;
        redS[ty * 2 + i][tx] = sloc;
    }
    __syncthreads();
    if (t < AT) {
        float M = -3.0e38f;
        #pragma unroll
        for (int i = 0; i < 16; i++) M = fmaxf(M, redM[t][i]);
        float S = 0.f;
        #pragma unroll
        for (int i = 0; i < 16; i++) S += redS[t][i] * expf(redM[t][i] - M);
        ws[OFF_PM + (size_t)wt * QALL + abase + t] = M;
        ws[OFF_PS + (size_t)wt * QALL + abase + t] = S;
    }
}

// ---------------- combine emit partials -> lse per row ----------------
__global__ __launch_bounds__(256) void lse_kernel(float* __restrict__ ws) {
    int a = threadIdx.x;
    float M = -3.0e38f;
    for (int wt = 0; wt < NWT; wt++) M = fmaxf(M, ws[OFF_PM + (size_t)wt * QALL + a]);
    float S = 0.f;
    for (int wt = 0; wt < NWT; wt++)
        S += ws[OFF_PS + (size_t)wt * QALL + a] * expf(ws[OFF_PM + (size_t)wt * QALL + a] - M);
    ws[OFF_LSE + a] = M + logf(S);
}

// ---------------- chart level 0: emit_lp[a, words[b,t]] + split1[a] ----------------
__global__ __launch_bounds__(256) void chart0_kernel(
        const int* __restrict__ words, const float* __restrict__ nt_emb,
        const float* __restrict__ W_emit, const float* __restrict__ b_emit,
        float* __restrict__ ws) {
    int blk = blockIdx.x;            // b*16 + tp
    int b = blk >> 4, tp = blk & 15;
    int a = threadIdx.x;
    int w = words[b * T_ + tp];
    const float* arow = &nt_emb[a * STATE];
    float acc = 0.f;
    #pragma unroll 8
    for (int s = 0; s < STATE; s++) acc += arow[s] * W_emit[s * VOCAB + w];
    float val = acc + b_emit[w] - ws[OFF_LSE + a] + ws[OFF_S1 + a];
    ws[chIdx(0, tp, b) + a] = val;
}

// ---------------- fused per-level DP: one block owns one (s,b) cell ----------------
// Phase A restructured: bulk LDS load (no per-k barriers), wave-parallel maxes,
// single-pass exp. ~7 barriers/block instead of ~80, phase A no longer duplicated
// 4x across sub-blocks, finalize inlined (no PART round-trip, 1 launch per level).
// Summation grouping matches the old Sred/part order (numerics preserved).
__global__ __launch_bounds__(512) void level_kernel(float* __restrict__ ws,
                                                    const int* __restrict__ argpc,
                                                    const int* __restrict__ res2all, int ell) {
    __shared__ __align__(16) float eAL[15 * 256];   // L rows: raw then exp(. - mL[k])
    __shared__ __align__(16) float eAR[15 * 256];   // R rows: raw then exp(. - mR[k])
    __shared__ __align__(16) float eBR[15 * QARG];  // R gathered at argpc: exp(. - (m - mL[k]))
    __shared__ __align__(16) float eBL[15 * QARG];  // L gathered at argpc: exp(. - (m - mR[k]))
    __shared__ float mL[15], mR[15];
    __shared__ float Sred[512];
    __shared__ float outrow[256];
    int sb = blockIdx.x;
    int s = sb >> 3, b = sb & 7;
    int t = threadIdx.x;
    int K = ell - 1;
    int side = t >> 8;       // 0: L-side threads, 1: R-side threads
    int u = t & 255;
    // phase A1: bulk load all K rows of both sides (independent, coalesced)
    for (int kp = 0; kp < K; kp++) {
        int k = kp + 1;
        if (side == 0) eAL[kp * 256 + u] = ws[chIdx(k - 1, s, b) + u];
        else           eAR[kp * 256 + u] = ws[chIdx(ell - k - 1, s + k, b) + u];
    }
    __syncthreads();
    // phase A2: wave-parallel per-k maxes (8 waves cover K<=15 k-values)
    int w = t >> 6, lane = t & 63;
    for (int kp = w; kp < K; kp += 8) {
        const float* pl = &eAL[kp * 256];
        float vl = fmaxf(fmaxf(pl[lane], pl[lane + 64]), fmaxf(pl[lane + 128], pl[lane + 192]));
        vl = waveMax(vl);
        const float* pr = &eAR[kp * 256];
        float vr = fmaxf(fmaxf(pr[lane], pr[lane + 64]), fmaxf(pr[lane + 128], pr[lane + 192]));
        vr = waveMax(vr);
        if (lane == 0) { mL[kp] = vl; mR[kp] = vr; }
    }
    __syncthreads();
    float m = -3.0e38f;
    for (int kp = 0; kp < K; kp++) m = fmaxf(m, mL[kp] + mR[kp]);
    // phase A3: gather raw broadcast-side values at argpc (before exp overwrites)
    bool doB = (u < QARG);
    int ap = doB ? argpc[u] : 0;
    if (doB) {
        if (side == 0) for (int kp = 0; kp < K; kp++) eBR[kp * QARG + u] = eAR[kp * 256 + ap];
        else           for (int kp = 0; kp < K; kp++) eBL[kp * QARG + u] = eAL[kp * 256 + ap];
    }
    __syncthreads();
    // phase B: exponentiate in place
    for (int kp = 0; kp < K; kp++) {
        if (side == 0) eAL[kp * 256 + u] = expf(eAL[kp * 256 + u] - mL[kp]);
        else           eAR[kp * 256 + u] = expf(eAR[kp * 256 + u] - mR[kp]);
    }
    if (doB) {
        for (int kp = 0; kp < K; kp++) {
            if (side == 0) eBR[kp * QARG + u] = expf(eBR[kp * QARG + u] - (m - mL[kp]));
            else           eBL[kp * QARG + u] = expf(eBL[kp * QARG + u] - (m - mR[kp]));
        }
    }
    __syncthreads();
    // phase C: 4 groups of 128 threads: grp = which*2 + jhalf, 96 j each, all k
    int r = t & 127, grp = t >> 7;
    int which = grp >> 1;
    int j0 = (grp & 1) * 96;
    const float* eGT = ws + (which == 0 ? OFF_EGR : OFF_EGL);
    const int* idxT = ((const int*)ws) + (which == 0 ? OFF_LF : OFF_RF);
    const float* gA = which ? eAR : eAL;
    const float* gB = which ? eBL : eBR;
    float accs[2];
    #pragma unroll
    for (int hh = 0; hh < 2; hh++) {
        float acc = 0.f;
        for (int jc = 0; jc < 48; jc += 4) {
            int j = j0 + hh * 48 + jc;
            float g0 = eGT[(size_t)(j + 0) * QRES + r];
            float g1 = eGT[(size_t)(j + 1) * QRES + r];
            float g2 = eGT[(size_t)(j + 2) * QRES + r];
            float g3 = eGT[(size_t)(j + 3) * QRES + r];
            int i0 = idxT[(size_t)(j + 0) * QRES + r];
            int i1 = idxT[(size_t)(j + 1) * QRES + r];
            int i2 = idxT[(size_t)(j + 2) * QRES + r];
            int i3 = idxT[(size_t)(j + 3) * QRES + r];
            float t0 = 0.f, t1 = 0.f, t2 = 0.f, t3 = 0.f;
            for (int kp = 0; kp < K; kp++) {
                const float* gs = &gA[kp * 256];
                float4 e4 = *(const float4*)&gB[kp * QARG + j];
                t0 += gs[i0] * e4.x;
                t1 += gs[i1] * e4.y;
                t2 += gs[i2] * e4.z;
                t3 += gs[i3] * e4.w;
            }
            acc += g0 * t0 + g1 * t1 + g2 * t2 + g3 * t3;
        }
        accs[hh] = acc;
    }
    Sred[t] = accs[0] + accs[1];
    __syncthreads();
    // finalize inline
    if (t < 256) outrow[t] = NEGV;
    __syncthreads();
    if (t < QRES) {
        float S = Sred[t] + Sred[128 + t] + Sred[256 + t] + Sred[384 + t];
        float parent = logf(S) + m + ws[OFF_S0 + res2all[t]];
        outrow[res2all[t]] = parent;
    }
    __syncthreads();
    if (t < 256) ws[chIdx(ell - 1, s, b) + t] = outrow[t];
}

// ---------------- root: logsumexp(chart[T-1,0,b] + log_softmax(root_w+root_b)) ----------------
__global__ __launch_bounds__(256) void root_kernel(const float* __restrict__ root_w,
                                                   const float* __restrict__ root_b,
                                                   const float* __restrict__ ws,
                                                   float* __restrict__ out) {
    int b = blockIdx.x, t = threadIdx.x;
    __shared__ float scr[4];
    float rv = root_w[t] + root_b[t];
    float mroot = blockMax(rv, scr, 4);
    float sroot = blockSum(expf(rv - mroot), scr, 4);
    float lroot = mroot + logf(sroot);
    float v = ws[chIdx(T_ - 1, 0, b) + t] + rv - lroot;
    float m2 = blockMax(v, scr, 4);
    float s2 = blockSum(expf(v - m2), scr, 4);
    if (t == 0) out[b] = m2 + logf(s2);
}

extern "C" void kernel_launch(void* const* d_in, const int* in_sizes, int n_in,
                              void* d_out, int out_size, void* d_ws, size_t ws_size,
                              hipStream_t stream) {
    const int*   words   = (const int*)  d_in[0];
    const float* nt_emb  = (const float*)d_in[1];
    const float* W_emit  = (const float*)d_in[2];
    const float* b_emit  = (const float*)d_in[3];
    const float* rule_W  = (const float*)d_in[4];
    const float* rule_b  = (const float*)d_in[5];
    const float* assoc   = (const float*)d_in[6];
    const float* root_w  = (const float*)d_in[7];
    const float* root_b  = (const float*)d_in[8];
    const float* sw1     = (const float*)d_in[9];
    const float* sb1     = (const float*)d_in[10];
    const float* r1w1    = (const float*)d_in[11];
    const float* r1b1    = (const float*)d_in[12];
    const float* r1w2    = (const float*)d_in[13];
    const float* r1b2    = (const float*)d_in[14];
    const float* r2w1    = (const float*)d_in[15];
    const float* r2b1    = (const float*)d_in[16];
    const float* r2w2    = (const float*)d_in[17];
    const float* r2b2    = (const float*)d_in[18];
    const float* sw2     = (const float*)d_in[19];
    const float* sb2     = (const float*)d_in[20];
    const int*   lfunc   = (const int*)  d_in[21];
    const int*   rfunc   = (const int*)  d_in[22];
    const int*   argpc   = (const int*)  d_in[23];
    const int*   res2all = (const int*)  d_in[24];
    const float* larg_m  = (const float*)d_in[25];
    const float* rarg_m  = (const float*)d_in[26];
    float* ws  = (float*)d_ws;
    float* out = (float*)d_out;

    prep_g_kernel<<<dim3(QRES), dim3(QARG), 0, stream>>>(rule_W, rule_b, assoc, larg_m, rarg_m,
                                                         lfunc, rfunc, ws);
    mlp_kernel<<<dim3(QALL), dim3(1024), 0, stream>>>(nt_emb, sw1, sb1, r1w1, r1b1, r1w2, r1b2,
                                                      r2w1, r2b1, r2w2, r2b2, sw2, sb2, ws);
    emit_kernel<<<dim3(NWT, QALL / AT), dim3(256), 0, stream>>>(nt_emb, W_emit, b_emit, ws);
    lse_kernel<<<dim3(1), dim3(256), 0, stream>>>(ws);
    chart0_kernel<<<dim3(B_ * T_), dim3(256), 0, stream>>>(words, nt_emb, W_emit, b_emit, ws);
    for (int ell = 2; ell <= T_; ell++) {
        int n = T_ - ell + 1;
        level_kernel<<<dim3(n * 8), dim3(512), 0, stream>>>(ws, argpc, res2all, ell);
    }
    root_kernel<<<dim3(B_), dim3(256), 0, stream>>>(root_w, root_b, ws, out);
}

// Round 4
// 420.712 us; speedup vs baseline: 1.4542x; 1.4542x over previous
//
#include <hip/hip_runtime.h>
#include <math.h>

#define NEGV -10000000.0f

constexpr int B_ = 8, T_ = 16;
constexpr int QALL = 256, QRES = 128, QARG = 192;
constexpr int STATE = 256, VOCAB = 10000;
constexpr int WT = 128;
constexpr int NWT = (VOCAB + WT - 1) / WT;   // 79

// ---- workspace layout (units of 4 bytes) ----
constexpr size_t OFF_CHART = 0;                                    // chart[ell][s][b][a]
constexpr size_t CHART_SZ  = (size_t)T_ * T_ * B_ * QALL;          // 524288
constexpr size_t OFF_EGR   = OFF_CHART + CHART_SZ;                 // exp(G_rarg) [j][r]
constexpr size_t OFF_EGL   = OFF_EGR + (size_t)QARG * QRES;        // exp(G_larg) [j][r]
constexpr size_t OFF_LF    = OFF_EGL + (size_t)QARG * QRES;        // lfunc transposed [j][r] (int)
constexpr size_t OFF_RF    = OFF_LF + (size_t)QARG * QRES;         // rfunc transposed [j][r] (int)
constexpr size_t OFF_S0    = OFF_RF + (size_t)QARG * QRES;         // split[:,0] per a (256)
constexpr size_t OFF_S1    = OFF_S0 + QALL;                        // split[:,1] per a (256)
constexpr size_t OFF_LSE   = OFF_S1 + QALL;                        // emit row lse (256)
constexpr size_t OFF_PMIT  = OFF_LSE + QALL;                       // emit partial max [wt][a]
constexpr size_t OFF_PSEM  = OFF_PMIT + (size_t)NWT * QALL;        // emit partial sum [wt][a]
// DP partial ping-pong buffers OVERLAY the emit PM/PS region (dead after chart0).
// Max partials per level = 352 (at ell=6: 88 cells x 2 jh x 2 kc).
constexpr int    PMAXP     = 352;
constexpr size_t OFF_P0S   = OFF_PMIT;                             // [352][128]
constexpr size_t OFF_P0M   = OFF_P0S + (size_t)PMAXP * QRES;       // [352]
constexpr size_t OFF_P1S   = OFF_P0M + PMAXP;
constexpr size_t OFF_P1M   = OFF_P1S + (size_t)PMAXP * QRES;
// end = OFF_P1M + 352 = ~714k floats (~2.86 MB) <= previous footprint

__device__ __forceinline__ size_t chIdx(int ell, int s, int b) {
    return OFF_CHART + ((size_t)((ell * 16 + s) * 8 + b)) * 256;
}

__device__ __forceinline__ float waveMax(float v) {
    #pragma unroll
    for (int m = 32; m >= 1; m >>= 1) v = fmaxf(v, __shfl_xor(v, m, 64));
    return v;
}
__device__ __forceinline__ float waveSum(float v) {
    #pragma unroll
    for (int m = 32; m >= 1; m >>= 1) v += __shfl_xor(v, m, 64);
    return v;
}
__device__ __forceinline__ float blockMax(float v, float* scr, int nw) {
    int lane = threadIdx.x & 63, w = threadIdx.x >> 6;
    v = waveMax(v);
    if (lane == 0) scr[w] = v;
    __syncthreads();
    float r = scr[0];
    for (int i = 1; i < nw; i++) r = fmaxf(r, scr[i]);
    __syncthreads();
    return r;
}
__device__ __forceinline__ float blockSum(float v, float* scr, int nw) {
    int lane = threadIdx.x & 63, w = threadIdx.x >> 6;
    v = waveSum(v);
    if (lane == 0) scr[w] = v;
    __syncthreads();
    float r = 0.f;
    for (int i = 0; i < nw; i++) r += scr[i];
    __syncthreads();
    return r;
}

// ---------------- G tables ----------------
__global__ __launch_bounds__(192) void prep_g_kernel(
        const float* __restrict__ rule_W, const float* __restrict__ rule_b,
        const float* __restrict__ assoc,
        const float* __restrict__ larg_mask, const float* __restrict__ rarg_mask,
        const int* __restrict__ lfunc, const int* __restrict__ rfunc,
        float* __restrict__ ws) {
    __shared__ float scr[4];
    int r = blockIdx.x;      // 0..127
    int j = threadIdx.x;     // 0..191
    float v0 = rule_W[r * 2 * QARG + j] + rule_b[j];
    float v1 = rule_W[r * 2 * QARG + QARG + j] + rule_b[QARG + j];
    float m = blockMax(fmaxf(v0, v1), scr, 3);
    float s = blockSum(expf(v0 - m) + expf(v1 - m), scr, 3);
    float l = m + logf(s);
    float av = assoc[r * QARG + j];
    float gl = v0 - l + av + larg_mask[r * QARG + j];
    float gr = v1 - l + av + rarg_mask[r * QARG + j];
    ws[OFF_EGL + (size_t)j * QRES + r] = expf(gl);
    ws[OFF_EGR + (size_t)j * QRES + r] = expf(gr);
    ((int*)ws)[OFF_LF + (size_t)j * QRES + r] = lfunc[r * QARG + j];
    ((int*)ws)[OFF_RF + (size_t)j * QRES + r] = rfunc[r * QARG + j];
}

// ---------------- split-score MLP (1024 threads, split-K x4) ----------------
#define MLP_MATVEC(INBUF, W, RES) do {                                          \
    float acc_ = 0.f;                                                           \
    _Pragma("unroll 16")                                                        \
    for (int s_ = 0; s_ < 64; s_++)                                             \
        acc_ += INBUF[s0 + s_] * W[(s0 + s_) * STATE + col];                    \
    part[t] = acc_;                                                             \
    __syncthreads();                                                            \
    RES = part[col] + part[STATE + col] + part[2 * STATE + col]                 \
        + part[3 * STATE + col];                                                \
} while (0)

__global__ __launch_bounds__(1024) void mlp_kernel(
        const float* __restrict__ nt_emb,
        const float* __restrict__ sw1, const float* __restrict__ sb1,
        const float* __restrict__ r1w1, const float* __restrict__ r1b1,
        const float* __restrict__ r1w2, const float* __restrict__ r1b2,
        const float* __restrict__ r2w1, const float* __restrict__ r2b1,
        const float* __restrict__ r2w2, const float* __restrict__ r2b2,
        const float* __restrict__ sw2, const float* __restrict__ sb2,
        float* __restrict__ ws) {
    __shared__ float xin[STATE], hbuf[STATE], tbuf[STATE];
    __shared__ float part[4 * STATE];
    __shared__ float scr[16];
    int a = blockIdx.x, t = threadIdx.x;
    int col = t & 255;
    int grp = t >> 8;
    int s0 = grp * 64;
    if (t < STATE) xin[t] = nt_emb[a * STATE + t];
    __syncthreads();
    float r;
    MLP_MATVEC(xin, sw1, r);
    if (grp == 0) hbuf[col] = r + sb1[col];
    __syncthreads();
    MLP_MATVEC(hbuf, r1w1, r);
    if (grp == 0) tbuf[col] = fmaxf(r + r1b1[col], 0.f);
    __syncthreads();
    MLP_MATVEC(tbuf, r1w2, r);
    if (grp == 0) hbuf[col] += fmaxf(r + r1b2[col], 0.f);
    __syncthreads();
    MLP_MATVEC(hbuf, r2w1, r);
    if (grp == 0) tbuf[col] = fmaxf(r + r2b1[col], 0.f);
    __syncthreads();
    MLP_MATVEC(tbuf, r2w2, r);
    if (grp == 0) hbuf[col] += fmaxf(r + r2b2[col], 0.f);
    __syncthreads();
    float hv = (t < STATE) ? hbuf[t] : 0.f;
    float v0 = (t < STATE) ? hv * sw2[t * 2 + 0] : 0.f;
    float v1 = (t < STATE) ? hv * sw2[t * 2 + 1] : 0.f;
    float u0 = blockSum(v0, scr, 16) + sb2[0];
    float u1 = blockSum(v1, scr, 16) + sb2[1];
    if (t == 0) {
        float mm = fmaxf(u0, u1);
        float l = mm + logf(expf(u0 - mm) + expf(u1 - mm));
        ws[OFF_S0 + a] = u0 - l;
        ws[OFF_S1 + a] = u1 - l;
    }
}

// ---------------- emit GEMM (round-1 config: 64 a-rows/block, 316 blocks) ----------------
__global__ __launch_bounds__(256) void emit_kernel(
        const float* __restrict__ nt_emb, const float* __restrict__ W_emit,
        const float* __restrict__ b_emit, float* __restrict__ ws) {
    __shared__ float As[16][64];
    __shared__ float Bs[16][128];
    __shared__ float redM[64][16], redS[64][16];
    int wt = blockIdx.x, at = blockIdx.y;
    int t = threadIdx.x;
    int tx = t & 15, ty = t >> 4;
    float acc[4][8];
    #pragma unroll
    for (int i = 0; i < 4; i++)
        #pragma unroll
        for (int j = 0; j < 8; j++) acc[i][j] = 0.f;
    int wbase = wt * WT, abase = at * 64;
    for (int k0 = 0; k0 < STATE; k0 += 16) {
        {
            int idx = t * 4;
            int kk = idx & 15, aa = idx >> 4;
            float4 v = *(const float4*)&nt_emb[(abase + aa) * STATE + k0 + kk];
            As[kk + 0][aa] = v.x; As[kk + 1][aa] = v.y; As[kk + 2][aa] = v.z; As[kk + 3][aa] = v.w;
        }
        {
            int idx = t * 8;
            int kk = idx >> 7, ww = idx & 127;
            int w = wbase + ww;
            const float* src = &W_emit[(k0 + kk) * VOCAB + w];
            float4 v0, v1;
            if (w + 7 < VOCAB) {
                v0 = *(const float4*)src;
                v1 = *(const float4*)(src + 4);
            } else {
                float tv[8];
                #pragma unroll
                for (int q = 0; q < 8; q++) tv[q] = (w + q < VOCAB) ? src[q] : 0.f;
                v0 = make_float4(tv[0], tv[1], tv[2], tv[3]);
                v1 = make_float4(tv[4], tv[5], tv[6], tv[7]);
            }
            float* dst = &Bs[kk][ww];
            ((float4*)dst)[0] = v0;
            ((float4*)dst)[1] = v1;
        }
        __syncthreads();
        #pragma unroll
        for (int kk = 0; kk < 16; kk++) {
            float a4[4], b8[8];
            #pragma unroll
            for (int i = 0; i < 4; i++) a4[i] = As[kk][ty * 4 + i];
            #pragma unroll
            for (int j = 0; j < 8; j++) b8[j] = Bs[kk][tx * 8 + j];
            #pragma unroll
            for (int i = 0; i < 4; i++)
                #pragma unroll
                for (int j = 0; j < 8; j++) acc[i][j] += a4[i] * b8[j];
        }
        __syncthreads();
    }
    float be[8];
    #pragma unroll
    for (int j = 0; j < 8; j++) {
        int w = wbase + tx * 8 + j;
        be[j] = (w < VOCAB) ? b_emit[w] : 0.f;
    }
    #pragma unroll
    for (int i = 0; i < 4; i++) {
        float mloc = -3.0e38f;
        #pragma unroll
        for (int j = 0; j < 8; j++) {
            int w = wbase + tx * 8 + j;
            if (w < VOCAB) {
                float v = acc[i][j] + be[j];
                acc[i][j] = v;
                mloc = fmaxf(mloc, v);
            }
        }
        float sloc = 0.f;
        #pragma unroll
        for (int j = 0; j < 8; j++) {
            int w = wbase + tx * 8 + j;
            if (w < VOCAB) sloc += expf(acc[i][j] - mloc);
        }
        redM[ty * 4 + i][tx] = mloc;
        redS[ty * 4 + i][tx] = sloc;
    }
    __syncthreads();
    if (t < 64) {
        float M = -3.0e38f;
        #pragma unroll
        for (int i = 0; i < 16; i++) M = fmaxf(M, redM[t][i]);
        float S = 0.f;
        #pragma unroll
        for (int i = 0; i < 16; i++) S += redS[t][i] * expf(redM[t][i] - M);
        ws[OFF_PMIT + (size_t)wt * QALL + abase + t] = M;
        ws[OFF_PSEM + (size_t)wt * QALL + abase + t] = S;
    }
}

// ---------------- combine emit partials -> lse per row ----------------
__global__ __launch_bounds__(256) void lse_kernel(float* __restrict__ ws) {
    int a = threadIdx.x;
    float M = -3.0e38f;
    for (int wt = 0; wt < NWT; wt++) M = fmaxf(M, ws[OFF_PMIT + (size_t)wt * QALL + a]);
    float S = 0.f;
    for (int wt = 0; wt < NWT; wt++)
        S += ws[OFF_PSEM + (size_t)wt * QALL + a] * expf(ws[OFF_PMIT + (size_t)wt * QALL + a] - M);
    ws[OFF_LSE + a] = M + logf(S);
}

// ---------------- chart level 0 ----------------
__global__ __launch_bounds__(256) void chart0_kernel(
        const int* __restrict__ words, const float* __restrict__ nt_emb,
        const float* __restrict__ W_emit, const float* __restrict__ b_emit,
        float* __restrict__ ws) {
    int blk = blockIdx.x;
    int b = blk >> 4, tp = blk & 15;
    int a = threadIdx.x;
    int w = words[b * T_ + tp];
    const float* arow = &nt_emb[a * STATE];
    float acc = 0.f;
    #pragma unroll 8
    for (int s = 0; s < STATE; s++) acc += arow[s] * W_emit[s * VOCAB + w];
    float val = acc + b_emit[w] - ws[OFF_LSE + a] + ws[OFF_S1 + a];
    ws[chIdx(0, tp, b) + a] = val;
}

// ---------------- per-level DP, k-chunked for constant parallelism ----------------
// One launch per level. Blocks:
//  - materializers [0, matCount): finalize prev level's rows from its partials -> chart
//  - accumulators: each handles (cell, j-half of 96, k-chunk of <=4), with a LOCAL
//    scale mc = max_k(mL+mR) over its chunk; writes 128-wide partial S + mc.
//    Rows from the prev level (k==1 R-row, k==K L-row) are reconstructed on the
//    fly from prev partials (logsumexp combine) - no cross-block sync needed.
// Partials ping-pong between two buffers by level parity.
__device__ __forceinline__ void reconRow(float* row, const float* __restrict__ ws,
                                         size_t prevS, size_t prevM, int cellp, int KCp,
                                         const int* __restrict__ res2all) {
    int t = threadIdx.x;
    int np = 2 * KCp;
    size_t base = (size_t)cellp * np;
    if (t < 256) row[t] = NEGV;
    float M = -3.0e38f;
    for (int p = 0; p < np; p++) M = fmaxf(M, ws[prevM + base + p]);
    __syncthreads();
    if (t < QRES) {
        float S = 0.f;
        for (int p = 0; p < np; p++)
            S += expf(ws[prevM + base + p] - M) * ws[prevS + (base + p) * QRES + t];
        row[res2all[t]] = logf(S) + M + ws[OFF_S0 + res2all[t]];
    }
    __syncthreads();
}

__global__ __launch_bounds__(512) void level_kernel(float* __restrict__ ws,
                                                    const int* __restrict__ argpc,
                                                    const int* __restrict__ res2all, int ell) {
    __shared__ __align__(16) float rowL[4][256], rowR[4][256];
    __shared__ __align__(16) float eB0[4][96], eB1[4][96];
    __shared__ float mLs[4], mRs[4];
    __shared__ float Sred[512];
    __shared__ float outrow[256];

    int K = ell - 1;
    int KC = (K + 3) >> 2;
    int matCount = (ell >= 3) ? (T_ - ell + 2) * 8 : 0;
    int t = threadIdx.x;
    int bid = blockIdx.x;

    int ellp = ell - 1;
    int KCp = (ellp - 1 + 3) >> 2;                  // prev level's k-chunks (ell>=3 paths only)
    size_t prevS = (ellp & 1) ? OFF_P1S : OFF_P0S;
    size_t prevM = (ellp & 1) ? OFF_P1M : OFF_P0M;
    size_t curS  = (ell & 1) ? OFF_P1S : OFF_P0S;
    size_t curM  = (ell & 1) ? OFF_P1M : OFF_P0M;

    if (bid < matCount) {
        // materialize prev-level row into chart
        int cellp = bid;
        int sp = cellp >> 3, bp = cellp & 7;
        reconRow(outrow, ws, prevS, prevM, cellp, KCp, res2all);
        if (t < 256) ws[chIdx(ellp - 1, sp, bp) + t] = outrow[t];
        return;
    }

    int aid = bid - matCount;
    int kc = aid % KC;
    int rem = aid / KC;
    int jh = rem & 1;
    int cell = rem >> 1;
    int s = cell >> 3, b = cell & 7;
    int k0 = kc * 4 + 1;                 // 1-based first k of chunk
    int kn = min(4, K - kc * 4);
    int j0 = jh * 96;
    int side = t >> 8, u = t & 255;

    // 1. bulk-load rows that are already materialized
    for (int kp = 0; kp < kn; kp++) {
        int k = k0 + kp;
        bool Lprev = (ell >= 3) && (k == K);
        bool Rprev = (ell >= 3) && (k == 1);
        if (!Lprev && side == 0) rowL[kp][u] = ws[chIdx(k - 1, s, b) + u];
        if (!Rprev && side == 1) rowR[kp][u] = ws[chIdx(ell - k - 1, s + k, b) + u];
    }
    // recon prev-level rows from partials (block-uniform conditions)
    for (int kp = 0; kp < kn; kp++) {
        int k = k0 + kp;
        if ((ell >= 3) && (k == K)) reconRow(&rowL[kp][0], ws, prevS, prevM, s * 8 + b, KCp, res2all);
        if ((ell >= 3) && (k == 1)) reconRow(&rowR[kp][0], ws, prevS, prevM, (s + 1) * 8 + b, KCp, res2all);
    }
    __syncthreads();

    // 2. per-k row maxes (wave w: kp=w>>1, side=w&1)
    int w = t >> 6, lane = t & 63;
    if (w < 2 * kn) {
        int kp = w >> 1;
        const float* pr = (w & 1) ? &rowR[kp][0] : &rowL[kp][0];
        float v = fmaxf(fmaxf(pr[lane], pr[lane + 64]), fmaxf(pr[lane + 128], pr[lane + 192]));
        v = waveMax(v);
        if (lane == 0) { if (w & 1) mRs[kp] = v; else mLs[kp] = v; }
    }
    __syncthreads();
    float mc = -3.0e38f;
    for (int kp = 0; kp < kn; kp++) mc = fmaxf(mc, mLs[kp] + mRs[kp]);

    // 3. gather broadcast-side at argpc (RAW rows), exp with chunk scale
    for (int kp = 0; kp < kn; kp++) {
        if (t < 96) {
            int ap = argpc[j0 + t];
            eB0[kp][t] = expf(rowR[kp][ap] - (mc - mLs[kp]));
        } else if (t < 192) {
            int jj = t - 96;
            int ap = argpc[j0 + jj];
            eB1[kp][jj] = expf(rowL[kp][ap] - (mc - mRs[kp]));
        }
    }
    __syncthreads();

    // 4. exponentiate rows in place
    for (int kp = 0; kp < kn; kp++) {
        if (side == 0) rowL[kp][u] = expf(rowL[kp][u] - mLs[kp]);
        else           rowR[kp][u] = expf(rowR[kp][u] - mRs[kp]);
    }
    __syncthreads();

    // 5. accumulate: sub = which*2 + jq48; 48 j per thread, kn k's
    int r = t & 127, sub = t >> 7;
    int which = sub >> 1;
    int jb = j0 + (sub & 1) * 48;
    const float* eGT = ws + (which == 0 ? OFF_EGR : OFF_EGL);
    const int* idxT = ((const int*)ws) + (which == 0 ? OFF_LF : OFF_RF);
    const float (*gA)[256] = which ? rowR : rowL;
    const float (*gB)[96]  = which ? eB1 : eB0;
    float acc = 0.f;
    for (int jc = 0; jc < 48; jc += 4) {
        int j = jb + jc;
        int jj = j - j0;
        float g0 = eGT[(size_t)(j + 0) * QRES + r];
        float g1 = eGT[(size_t)(j + 1) * QRES + r];
        float g2 = eGT[(size_t)(j + 2) * QRES + r];
        float g3 = eGT[(size_t)(j + 3) * QRES + r];
        int i0 = idxT[(size_t)(j + 0) * QRES + r];
        int i1 = idxT[(size_t)(j + 1) * QRES + r];
        int i2 = idxT[(size_t)(j + 2) * QRES + r];
        int i3 = idxT[(size_t)(j + 3) * QRES + r];
        float t0 = 0.f, t1 = 0.f, t2 = 0.f, t3 = 0.f;
        for (int kp = 0; kp < kn; kp++) {
            const float* gs = gA[kp];
            float4 e4 = *(const float4*)&gB[kp][jj];
            t0 += gs[i0] * e4.x;
            t1 += gs[i1] * e4.y;
            t2 += gs[i2] * e4.z;
            t3 += gs[i3] * e4.w;
        }
        acc += g0 * t0 + g1 * t1 + g2 * t2 + g3 * t3;
    }
    Sred[t] = acc;
    __syncthreads();
    if (t < QRES) {
        float S = Sred[t] + Sred[128 + t] + Sred[256 + t] + Sred[384 + t];
        ws[curS + (size_t)aid * QRES + t] = S;
    }
    if (t == 0) ws[curM + aid] = mc;
}

// ---------------- root: reconstruct final row from level-16 partials, then lse ----------------
__global__ __launch_bounds__(256) void root_kernel(const float* __restrict__ root_w,
                                                   const float* __restrict__ root_b,
                                                   const float* __restrict__ ws,
                                                   const int* __restrict__ res2all,
                                                   float* __restrict__ out) {
    int b = blockIdx.x, t = threadIdx.x;
    __shared__ float scr[4];
    __shared__ float outrow[256];
    // level 16 partials: buffer parity 16&1=0; KC=4, 8 partials/cell, cell = b
    {
        int np = 8;
        size_t base = (size_t)b * np;
        outrow[t] = NEGV;
        float M = -3.0e38f;
        for (int p = 0; p < np; p++) M = fmaxf(M, ws[OFF_P0M + base + p]);
        __syncthreads();
        if (t < QRES) {
            float S = 0.f;
            for (int p = 0; p < np; p++)
                S += expf(ws[OFF_P0M + base + p] - M) * ws[OFF_P0S + (base + p) * QRES + t];
            outrow[res2all[t]] = logf(S) + M + ws[OFF_S0 + res2all[t]];
        }
        __syncthreads();
    }
    float rv = root_w[t] + root_b[t];
    float mroot = blockMax(rv, scr, 4);
    float sroot = blockSum(expf(rv - mroot), scr, 4);
    float lroot = mroot + logf(sroot);
    float v = outrow[t] + rv - lroot;
    float m2 = blockMax(v, scr, 4);
    float s2 = blockSum(expf(v - m2), scr, 4);
    if (t == 0) out[b] = m2 + logf(s2);
}

extern "C" void kernel_launch(void* const* d_in, const int* in_sizes, int n_in,
                              void* d_out, int out_size, void* d_ws, size_t ws_size,
                              hipStream_t stream) {
    const int*   words   = (const int*)  d_in[0];
    const float* nt_emb  = (const float*)d_in[1];
    const float* W_emit  = (const float*)d_in[2];
    const float* b_emit  = (const float*)d_in[3];
    const float* rule_W  = (const float*)d_in[4];
    const float* rule_b  = (const float*)d_in[5];
    const float* assoc   = (const float*)d_in[6];
    const float* root_w  = (const float*)d_in[7];
    const float* root_b  = (const float*)d_in[8];
    const float* sw1     = (const float*)d_in[9];
    const float* sb1     = (const float*)d_in[10];
    const float* r1w1    = (const float*)d_in[11];
    const float* r1b1    = (const float*)d_in[12];
    const float* r1w2    = (const float*)d_in[13];
    const float* r1b2    = (const float*)d_in[14];
    const float* r2w1    = (const float*)d_in[15];
    const float* r2b1    = (const float*)d_in[16];
    const float* r2w2    = (const float*)d_in[17];
    const float* r2b2    = (const float*)d_in[18];
    const float* sw2     = (const float*)d_in[19];
    const float* sb2     = (const float*)d_in[20];
    const int*   lfunc   = (const int*)  d_in[21];
    const int*   rfunc   = (const int*)  d_in[22];
    const int*   argpc   = (const int*)  d_in[23];
    const int*   res2all = (const int*)  d_in[24];
    const float* larg_m  = (const float*)d_in[25];
    const float* rarg_m  = (const float*)d_in[26];
    float* ws  = (float*)d_ws;
    float* out = (float*)d_out;

    prep_g_kernel<<<dim3(QRES), dim3(QARG), 0, stream>>>(rule_W, rule_b, assoc, larg_m, rarg_m,
                                                         lfunc, rfunc, ws);
    mlp_kernel<<<dim3(QALL), dim3(1024), 0, stream>>>(nt_emb, sw1, sb1, r1w1, r1b1, r1w2, r1b2,
                                                      r2w1, r2b1, r2w2, r2b2, sw2, sb2, ws);
    emit_kernel<<<dim3(NWT, QALL / 64), dim3(256), 0, stream>>>(nt_emb, W_emit, b_emit, ws);
    lse_kernel<<<dim3(1), dim3(256), 0, stream>>>(ws);
    chart0_kernel<<<dim3(B_ * T_), dim3(256), 0, stream>>>(words, nt_emb, W_emit, b_emit, ws);
    for (int ell = 2; ell <= T_; ell++) {
        int n = T_ - ell + 1;
        int K = ell - 1, KC = (K + 3) / 4;
        int matCount = (ell >= 3) ? (n + 1) * 8 : 0;
        int accCount = n * 8 * 2 * KC;
        level_kernel<<<dim3(matCount + accCount), dim3(512), 0, stream>>>(ws, argpc, res2all, ell);
    }
    root_kernel<<<dim3(B_), dim3(256), 0, stream>>>(root_w, root_b, ws, res2all, out);
}